// Round 3
// baseline (970.754 us; speedup 1.0000x reference)
//
#include <hip/hip_runtime.h>
#include <hip/hip_bf16.h>

typedef __attribute__((ext_vector_type(8))) short bf16x8;
typedef __attribute__((ext_vector_type(4))) float f32x4;
typedef unsigned short ushort_t;

#define AS1 __attribute__((address_space(1)))
#define AS3 __attribute__((address_space(3)))

__device__ __forceinline__ void gload_lds16(const void* g, void* l) {
    __builtin_amdgcn_global_load_lds((const AS1 void*)g, (AS3 void*)l, 16, 0, 0);
}

__device__ __forceinline__ ushort_t f2b(float f) {
    unsigned u = __builtin_bit_cast(unsigned, f);
    unsigned r = (u + 0x7FFFu + ((u >> 16) & 1u)) >> 16;
    return (ushort_t)r;
}

__device__ __forceinline__ float b2f(short s) {
    unsigned v = ((unsigned)(ushort_t)s) << 16;
    return __builtin_bit_cast(float, v);
}

// ---------------- convert x (fp32 -> bf16) ----------------
__global__ __launch_bounds__(256) void convert_x_kernel(const float* __restrict__ in,
                                                        ushort_t* __restrict__ out, int n4) {
    int i = blockIdx.x * blockDim.x + threadIdx.x;
    if (i < n4) {
        float4 f = ((const float4*)in)[i];
        ushort4 u;
        u.x = f2b(f.x); u.y = f2b(f.y); u.z = f2b(f.z); u.w = f2b(f.w);
        ((ushort4*)out)[i] = u;
    }
}

// ---------------- transpose + convert weight: W[K][N] fp32 -> WT[N][K] bf16 ----------------
__global__ __launch_bounds__(256) void transpose_w_kernel(const float* __restrict__ W,
                                                          ushort_t* __restrict__ WT) {
    __shared__ float t[32][33];
    int n0 = blockIdx.x * 32, k0 = blockIdx.y * 32;
    int tx = threadIdx.x, ty = threadIdx.y; // block (32,8)
    for (int i = 0; i < 4; ++i)
        t[ty + i * 8][tx] = W[(size_t)(k0 + ty + i * 8) * 1024 + n0 + tx];
    __syncthreads();
    for (int i = 0; i < 4; ++i)
        WT[(size_t)(n0 + ty + i * 8) * 1024 + k0 + tx] = f2b(t[tx][ty + i * 8]);
}

// ---------------- bf16 MFMA GEMM, 2-phase dbuf global_load_lds ----------------
// C[8192][N] = A[8192][1024] @ BT[N][1024]^T.
template <int N, int OUT_BF16>
__global__ __launch_bounds__(256) void gemm_kernel(const ushort_t* __restrict__ A,
                                                   const ushort_t* __restrict__ BT,
                                                   ushort_t* __restrict__ Cb,
                                                   float* __restrict__ Cf,
                                                   const float* __restrict__ bias) {
    const int K = 1024;
    __shared__ ushort_t As[2 * 128 * 32];
    __shared__ ushort_t Bs[2 * 128 * 32];
    int tid = threadIdx.x;
    int wid = tid >> 6, lane = tid & 63;
    int g = lane >> 4, lr = lane & 15;
    int m0 = blockIdx.x * 128, n0 = blockIdx.y * 128;
    int wm = wid >> 1, wn = wid & 1;

    f32x4 acc[4][4] = {};

    // staging geometry: chunk = 1 KB = 16 rows x 64 B; wave w owns chunks 2w, 2w+1
    int c0 = wid * 2;
    int lrow = lane >> 2;                              // row within chunk
    int lcol = ((lane & 3) ^ ((lane >> 3) & 3)) * 8;   // pre-swizzled source col (elems)
    const ushort_t* Ag0 = A  + (size_t)(m0 + c0 * 16 + lrow) * K + lcol;
    const ushort_t* Ag1 = A  + (size_t)(m0 + c0 * 16 + 16 + lrow) * K + lcol;
    const ushort_t* Bg0 = BT + (size_t)(n0 + c0 * 16 + lrow) * K + lcol;
    const ushort_t* Bg1 = BT + (size_t)(n0 + c0 * 16 + 16 + lrow) * K + lcol;

    int swzA = ((lr >> 1) & 3) << 4;   // fragment-read byte XOR

    auto stage = [&](int bufi, int kt) {
        char* a0 = (char*)As + bufi * 8192 + c0 * 1024;
        char* b0 = (char*)Bs + bufi * 8192 + c0 * 1024;
        gload_lds16(Ag0 + kt * 32, a0);
        gload_lds16(Ag1 + kt * 32, a0 + 1024);
        gload_lds16(Bg0 + kt * 32, b0);
        gload_lds16(Bg1 + kt * 32, b0 + 1024);
    };

    stage(0, 0);
    __syncthreads();
    int buf = 0;
    for (int kt = 0; kt < K / 32; ++kt) {
        if (kt + 1 < K / 32) stage(buf ^ 1, kt + 1);
        const char* ab = (const char*)As + buf * 8192;
        const char* bb = (const char*)Bs + buf * 8192;
        bf16x8 af[4], bfr[4];
#pragma unroll
        for (int m = 0; m < 4; ++m) {
            int row = wm * 64 + m * 16 + lr;
            af[m] = *(const bf16x8*)(ab + row * 64 + ((g * 16) ^ swzA));
        }
#pragma unroll
        for (int n = 0; n < 4; ++n) {
            int row = wn * 64 + n * 16 + lr;
            bfr[n] = *(const bf16x8*)(bb + row * 64 + ((g * 16) ^ swzA));
        }
#pragma unroll
        for (int m = 0; m < 4; ++m)
#pragma unroll
            for (int n = 0; n < 4; ++n)
                acc[m][n] = __builtin_amdgcn_mfma_f32_16x16x32_bf16(af[m], bfr[n], acc[m][n], 0, 0, 0);
        __syncthreads();
        buf ^= 1;
    }

#pragma unroll
    for (int m = 0; m < 4; ++m)
#pragma unroll
        for (int n = 0; n < 4; ++n) {
            int row0 = m0 + wm * 64 + m * 16 + g * 4;
            int col  = n0 + wn * 64 + n * 16 + lr;
#pragma unroll
            for (int r = 0; r < 4; ++r) {
                float v = acc[m][n][r];
                if (OUT_BF16)
                    Cb[(size_t)(row0 + r) * N + col] = f2b(v);
                else
                    Cf[(size_t)(row0 + r) * N + col] = v + bias[col];
            }
        }
}

// ---------------- V transpose: Cqkv V-part [s][d] -> Vt[b][h][d][s] bf16 ----------------
__global__ __launch_bounds__(256) void vt_kernel(const ushort_t* __restrict__ Cqkv,
                                                 ushort_t* __restrict__ Vt) {
    int b = blockIdx.z, h = blockIdx.y, st = blockIdx.x;
    __shared__ ushort_t t[64][72];
    const ushort_t* src = Cqkv + (size_t)b * 2048 * 3072 + 2048 + (size_t)h * 64;
    int tid = threadIdx.x;
#pragma unroll
    for (int i = 0; i < 2; ++i) {
        int c = tid + i * 256;          // 0..511
        int sl = c >> 3, dc = (c & 7) * 8;
        *(bf16x8*)&t[sl][dc] = *(const bf16x8*)(src + (size_t)(st * 64 + sl) * 3072 + dc);
    }
    __syncthreads();
#pragma unroll
    for (int i = 0; i < 2; ++i) {
        int c = tid + i * 256;
        int d = c >> 3, sc = (c & 7) * 8;
        bf16x8 v;
#pragma unroll
        for (int j = 0; j < 8; ++j) v[j] = (short)t[sc + j][d];
        *(bf16x8*)(Vt + ((size_t)(b * 16 + h) * 64 + d) * 2048 + st * 64 + sc) = v;
    }
}

// ---------------- fused attention, barrier-free ----------------
// grid (32 qtiles, 16 heads, 4 batch), block 256 (4 waves, 16 q-rows each).
// K and Vt MFMA fragments are read directly from global (L2/L3-resident);
// only P takes an LDS round-trip, produced & consumed by the SAME wave.
__global__ __launch_bounds__(256) void attn_kernel(const ushort_t* __restrict__ Cqkv,
                                                   const ushort_t* __restrict__ Vtg,
                                                   float* __restrict__ Pout,
                                                   ushort_t* __restrict__ Oout) {
    const int S = 2048, DQ = 3072;
    int b = blockIdx.z, h = blockIdx.y, qt = (int)blockIdx.x, q0 = qt * 64;
    int tid = threadIdx.x, wid = tid >> 6, lane = tid & 63;
    int g = lane >> 4, lr = lane & 15;

    __shared__ ushort_t Pb[64 * 64];
    char* PbB = (char*)Pb;

    const ushort_t* Qb = Cqkv + (size_t)b * S * DQ + (size_t)h * 64;
    const ushort_t* Kb = Cqkv + (size_t)b * S * DQ + 1024 + (size_t)h * 64;
    const ushort_t* Vb = Vtg + (size_t)((b * 16 + h) * 64) * 2048;
    float* Pbase = Pout + (((size_t)(b * 16 + h)) * S + q0) * S;

    bf16x8 qf[2];
    {
        const ushort_t* qp = Qb + (size_t)(q0 + wid * 16 + lr) * DQ + g * 8;
        qf[0] = *(const bf16x8*)qp;
        qf[1] = *(const bf16x8*)(qp + 32);
    }
    int qlg = wid * 16 + g * 4;   // local q-row base of this lane's outputs

    // ---- phase 1: row sum of exp(s-4), per-lane partials ----
    float psum[4] = {0.f, 0.f, 0.f, 0.f};
    for (int tt = 0; tt <= qt; ++tt) {
        const ushort_t* Kt = Kb + (size_t)tt * 64 * DQ;
        bf16x8 kfr[4][2];
#pragma unroll
        for (int nb = 0; nb < 4; ++nb) {
            const ushort_t* kp = Kt + (size_t)(nb * 16 + lr) * DQ + g * 8;
            kfr[nb][0] = *(const bf16x8*)kp;
            kfr[nb][1] = *(const bf16x8*)(kp + 32);
        }
#pragma unroll
        for (int nb = 0; nb < 4; ++nb) {
            f32x4 s = {};
            s = __builtin_amdgcn_mfma_f32_16x16x32_bf16(qf[0], kfr[nb][0], s, 0, 0, 0);
            s = __builtin_amdgcn_mfma_f32_16x16x32_bf16(qf[1], kfr[nb][1], s, 0, 0, 0);
            if (tt == qt) {
#pragma unroll
                for (int r = 0; r < 4; ++r)
                    if (nb * 16 + lr <= qlg + r) psum[r] += __expf(s[r] * 0.125f - 4.f);
            } else {
#pragma unroll
                for (int r = 0; r < 4; ++r) psum[r] += __expf(s[r] * 0.125f - 4.f);
            }
        }
    }
    float lnl[4];
#pragma unroll
    for (int r = 0; r < 4; ++r) {
        float v = psum[r];
        v += __shfl_xor(v, 1); v += __shfl_xor(v, 2);
        v += __shfl_xor(v, 4); v += __shfl_xor(v, 8);
        lnl[r] = __logf(v) + 4.f;
    }

    // ---- phase 2: P = exp(s*0.125 - lnl), write P + accumulate O ----
    f32x4 Oacc[4] = {};
    for (int tt = 0; tt <= qt; ++tt) {
        const ushort_t* Kt = Kb + (size_t)tt * 64 * DQ;
        bf16x8 kfr[4][2], vfr[4][2];
#pragma unroll
        for (int nb = 0; nb < 4; ++nb) {
            const ushort_t* kp = Kt + (size_t)(nb * 16 + lr) * DQ + g * 8;
            kfr[nb][0] = *(const bf16x8*)kp;
            kfr[nb][1] = *(const bf16x8*)(kp + 32);
            const ushort_t* vp = Vb + (size_t)(nb * 16 + lr) * 2048 + tt * 64 + g * 8;
            vfr[nb][0] = *(const bf16x8*)vp;
            vfr[nb][1] = *(const bf16x8*)(vp + 32);
        }
#pragma unroll
        for (int nb = 0; nb < 4; ++nb) {
            f32x4 s = {};
            s = __builtin_amdgcn_mfma_f32_16x16x32_bf16(qf[0], kfr[nb][0], s, 0, 0, 0);
            s = __builtin_amdgcn_mfma_f32_16x16x32_bf16(qf[1], kfr[nb][1], s, 0, 0, 0);
#pragma unroll
            for (int r = 0; r < 4; ++r) {
                float p = __expf(s[r] * 0.125f - lnl[r]);
                if (tt == qt && (nb * 16 + lr > qlg + r)) p = 0.f;
                int row = qlg + r;
                *(ushort_t*)(PbB + ((row * 128 + (nb * 16 + lr) * 2) ^ ((row & 7) << 4))) = f2b(p);
            }
        }
        __builtin_amdgcn_wave_barrier();
        // PV MFMA (A = P rows of THIS wave, B = Vt rows from global)
#pragma unroll
        for (int kc = 0; kc < 2; ++kc) {
            int prow = wid * 16 + lr;
            bf16x8 pf = *(const bf16x8*)(PbB + ((prow * 128 + kc * 64 + g * 16) ^ ((prow & 7) << 4)));
#pragma unroll
            for (int nb = 0; nb < 4; ++nb)
                Oacc[nb] = __builtin_amdgcn_mfma_f32_16x16x32_bf16(pf, vfr[nb][kc], Oacc[nb], 0, 0, 0);
        }
        // coalesced P global write, per-wave rows (64B per lane)
        {
            int rl = lane >> 2;
            int row = wid * 16 + rl;
            int c0 = (lane & 3) * 16;
            int x = (row & 7) << 4;
            bf16x8 p0 = *(const bf16x8*)(PbB + ((row * 128 + c0 * 2) ^ x));
            bf16x8 p1 = *(const bf16x8*)(PbB + ((row * 128 + c0 * 2 + 16) ^ x));
            float* dst = Pbase + (size_t)row * S + tt * 64 + c0;
            float4 w;
            w.x = b2f(p0[0]); w.y = b2f(p0[1]); w.z = b2f(p0[2]); w.w = b2f(p0[3]); ((float4*)dst)[0] = w;
            w.x = b2f(p0[4]); w.y = b2f(p0[5]); w.z = b2f(p0[6]); w.w = b2f(p0[7]); ((float4*)dst)[1] = w;
            w.x = b2f(p1[0]); w.y = b2f(p1[1]); w.z = b2f(p1[2]); w.w = b2f(p1[3]); ((float4*)dst)[2] = w;
            w.x = b2f(p1[4]); w.y = b2f(p1[5]); w.z = b2f(p1[6]); w.w = b2f(p1[7]); ((float4*)dst)[3] = w;
        }
        __builtin_amdgcn_wave_barrier();
    }

    // zero-fill strictly-upper tiles
    {
        int vsr = tid >> 2, vsc = (tid & 3) * 16;
        float4 z = {0.f, 0.f, 0.f, 0.f};
        for (int tt = qt + 1; tt < 32; ++tt) {
            float* dst = Pbase + (size_t)vsr * S + tt * 64 + vsc;
#pragma unroll
            for (int j = 0; j < 4; ++j) ((float4*)dst)[j] = z;
        }
    }

    // write O (bf16) as [B,S,H*Dh]
#pragma unroll
    for (int nb = 0; nb < 4; ++nb)
#pragma unroll
        for (int r = 0; r < 4; ++r) {
            int q = q0 + qlg + r;
            Oout[((size_t)b * S + q) * 1024 + h * 64 + nb * 16 + lr] = f2b(Oacc[nb][r]);
        }
}

extern "C" void kernel_launch(void* const* d_in, const int* in_sizes, int n_in,
                              void* d_out, int out_size, void* d_ws, size_t ws_size,
                              hipStream_t stream) {
    const float* x  = (const float*)d_in[0];
    const float* Wq = (const float*)d_in[1];
    const float* Wk = (const float*)d_in[2];
    const float* Wv = (const float*)d_in[3];
    const float* Wo = (const float*)d_in[4];
    const float* bo = (const float*)d_in[5];

    float* out  = (float*)d_out;
    float* Pout = out + (size_t)8388608; // attn_probs region

    char* ws = (char*)d_ws;
    ushort_t* xb    = (ushort_t*)(ws);                       // 16 MB
    ushort_t* wqkv  = (ushort_t*)(ws + (16u << 20));         // 6 MB [3072][1024]
    ushort_t* wob   = (ushort_t*)(ws + (22u << 20));         // 2 MB
    ushort_t* Cqkv  = (ushort_t*)(ws + (24u << 20));         // 48 MB [8192][3072]
    ushort_t* Vtw   = (ushort_t*)(ws + (72u << 20));         // 32 MB [64][64][2048]
    ushort_t* attnb = (ushort_t*)(ws + (104u << 20));        // 16 MB

    // 1. dtype conversions / weight transposes
    convert_x_kernel<<<8192, 256, 0, stream>>>(x, xb, 2097152);
    transpose_w_kernel<<<dim3(32, 32), dim3(32, 8), 0, stream>>>(Wq, wqkv);
    transpose_w_kernel<<<dim3(32, 32), dim3(32, 8), 0, stream>>>(Wk, wqkv + 1024 * 1024);
    transpose_w_kernel<<<dim3(32, 32), dim3(32, 8), 0, stream>>>(Wv, wqkv + 2 * 1024 * 1024);
    transpose_w_kernel<<<dim3(32, 32), dim3(32, 8), 0, stream>>>(Wo, wob);

    // 2. fused QKV projection: Cqkv[8192][3072]
    gemm_kernel<3072, 1><<<dim3(64, 24), 256, 0, stream>>>(xb, wqkv, Cqkv, nullptr, nullptr);

    // 3. V transpose to [b][h][d][s]
    vt_kernel<<<dim3(32, 16, 4), 256, 0, stream>>>(Cqkv, Vtw);

    // 4. attention (writes attn_probs fp32 + context bf16)
    attn_kernel<<<dim3(32, 16, 4), 256, 0, stream>>>(Cqkv, Vtw, Pout, attnb);

    // 5. output projection + bias (fp32 out)
    gemm_kernel<1024, 0><<<dim3(64, 8), 256, 0, stream>>>(attnb, wob, nullptr, out, bo);
}

// Round 4
// 556.258 us; speedup vs baseline: 1.7452x; 1.7452x over previous
//
#include <hip/hip_runtime.h>
#include <hip/hip_bf16.h>

typedef __attribute__((ext_vector_type(8))) short bf16x8;
typedef __attribute__((ext_vector_type(4))) float f32x4;
typedef unsigned short ushort_t;

#define AS1 __attribute__((address_space(1)))
#define AS3 __attribute__((address_space(3)))

__device__ __forceinline__ void gload_lds16(const void* g, void* l) {
    __builtin_amdgcn_global_load_lds((const AS1 void*)g, (AS3 void*)l, 16, 0, 0);
}

__device__ __forceinline__ ushort_t f2b(float f) {
    unsigned u = __builtin_bit_cast(unsigned, f);
    unsigned r = (u + 0x7FFFu + ((u >> 16) & 1u)) >> 16;
    return (ushort_t)r;
}

__device__ __forceinline__ float b2f(short s) {
    unsigned v = ((unsigned)(ushort_t)s) << 16;
    return __builtin_bit_cast(float, v);
}

// ---------------- convert x (fp32 -> bf16) ----------------
__global__ __launch_bounds__(256) void convert_x_kernel(const float* __restrict__ in,
                                                        ushort_t* __restrict__ out, int n4) {
    int i = blockIdx.x * blockDim.x + threadIdx.x;
    if (i < n4) {
        float4 f = ((const float4*)in)[i];
        ushort4 u;
        u.x = f2b(f.x); u.y = f2b(f.y); u.z = f2b(f.z); u.w = f2b(f.w);
        ((ushort4*)out)[i] = u;
    }
}

// ---------------- transpose + convert weight: W[K][N] fp32 -> WT[N][K] bf16 ----------------
__global__ __launch_bounds__(256) void transpose_w_kernel(const float* __restrict__ W,
                                                          ushort_t* __restrict__ WT) {
    __shared__ float t[32][33];
    int n0 = blockIdx.x * 32, k0 = blockIdx.y * 32;
    int tx = threadIdx.x, ty = threadIdx.y; // block (32,8)
    for (int i = 0; i < 4; ++i)
        t[ty + i * 8][tx] = W[(size_t)(k0 + ty + i * 8) * 1024 + n0 + tx];
    __syncthreads();
    for (int i = 0; i < 4; ++i)
        WT[(size_t)(n0 + ty + i * 8) * 1024 + k0 + tx] = f2b(t[tx][ty + i * 8]);
}

// ---------------- bf16 MFMA GEMM, 2-phase dbuf global_load_lds ----------------
template <int N, int OUT_BF16>
__global__ __launch_bounds__(256) void gemm_kernel(const ushort_t* __restrict__ A,
                                                   const ushort_t* __restrict__ BT,
                                                   ushort_t* __restrict__ Cb,
                                                   float* __restrict__ Cf,
                                                   const float* __restrict__ bias) {
    const int K = 1024;
    __shared__ ushort_t As[2 * 128 * 32];
    __shared__ ushort_t Bs[2 * 128 * 32];
    int tid = threadIdx.x;
    int wid = tid >> 6, lane = tid & 63;
    int g = lane >> 4, lr = lane & 15;
    int m0 = blockIdx.x * 128, n0 = blockIdx.y * 128;
    int wm = wid >> 1, wn = wid & 1;

    f32x4 acc[4][4] = {};

    int c0 = wid * 2;
    int lrow = lane >> 2;
    int lcol = ((lane & 3) ^ ((lane >> 3) & 3)) * 8;
    const ushort_t* Ag0 = A  + (size_t)(m0 + c0 * 16 + lrow) * K + lcol;
    const ushort_t* Ag1 = A  + (size_t)(m0 + c0 * 16 + 16 + lrow) * K + lcol;
    const ushort_t* Bg0 = BT + (size_t)(n0 + c0 * 16 + lrow) * K + lcol;
    const ushort_t* Bg1 = BT + (size_t)(n0 + c0 * 16 + 16 + lrow) * K + lcol;

    int swzA = ((lr >> 1) & 3) << 4;

    auto stage = [&](int bufi, int kt) {
        char* a0 = (char*)As + bufi * 8192 + c0 * 1024;
        char* b0 = (char*)Bs + bufi * 8192 + c0 * 1024;
        gload_lds16(Ag0 + kt * 32, a0);
        gload_lds16(Ag1 + kt * 32, a0 + 1024);
        gload_lds16(Bg0 + kt * 32, b0);
        gload_lds16(Bg1 + kt * 32, b0 + 1024);
    };

    stage(0, 0);
    __syncthreads();
    int buf = 0;
    for (int kt = 0; kt < K / 32; ++kt) {
        if (kt + 1 < K / 32) stage(buf ^ 1, kt + 1);
        const char* ab = (const char*)As + buf * 8192;
        const char* bb = (const char*)Bs + buf * 8192;
        bf16x8 af[4], bfr[4];
#pragma unroll
        for (int m = 0; m < 4; ++m) {
            int row = wm * 64 + m * 16 + lr;
            af[m] = *(const bf16x8*)(ab + row * 64 + ((g * 16) ^ swzA));
        }
#pragma unroll
        for (int n = 0; n < 4; ++n) {
            int row = wn * 64 + n * 16 + lr;
            bfr[n] = *(const bf16x8*)(bb + row * 64 + ((g * 16) ^ swzA));
        }
#pragma unroll
        for (int m = 0; m < 4; ++m)
#pragma unroll
            for (int n = 0; n < 4; ++n)
                acc[m][n] = __builtin_amdgcn_mfma_f32_16x16x32_bf16(af[m], bfr[n], acc[m][n], 0, 0, 0);
        __syncthreads();
        buf ^= 1;
    }

#pragma unroll
    for (int m = 0; m < 4; ++m)
#pragma unroll
        for (int n = 0; n < 4; ++n) {
            int row0 = m0 + wm * 64 + m * 16 + g * 4;
            int col  = n0 + wn * 64 + n * 16 + lr;
#pragma unroll
            for (int r = 0; r < 4; ++r) {
                float v = acc[m][n][r];
                if (OUT_BF16)
                    Cb[(size_t)(row0 + r) * N + col] = f2b(v);
                else
                    Cf[(size_t)(row0 + r) * N + col] = v + bias[col];
            }
        }
}

// ---------------- V transpose: Cqkv V-part [s][d] -> Vt[b][h][d][s] bf16 ----------------
__global__ __launch_bounds__(256) void vt_kernel(const ushort_t* __restrict__ Cqkv,
                                                 ushort_t* __restrict__ Vt) {
    int b = blockIdx.z, h = blockIdx.y, st = blockIdx.x;
    __shared__ ushort_t t[64][72];
    const ushort_t* src = Cqkv + (size_t)b * 2048 * 3072 + 2048 + (size_t)h * 64;
    int tid = threadIdx.x;
#pragma unroll
    for (int i = 0; i < 2; ++i) {
        int c = tid + i * 256;
        int sl = c >> 3, dc = (c & 7) * 8;
        *(bf16x8*)&t[sl][dc] = *(const bf16x8*)(src + (size_t)(st * 64 + sl) * 3072 + dc);
    }
    __syncthreads();
#pragma unroll
    for (int i = 0; i < 2; ++i) {
        int c = tid + i * 256;
        int d = c >> 3, sc = (c & 7) * 8;
        bf16x8 v;
#pragma unroll
        for (int j = 0; j < 8; ++j) v[j] = (short)t[sc + j][d];
        *(bf16x8*)(Vt + ((size_t)(b * 16 + h) * 64 + d) * 2048 + st * 64 + sc) = v;
    }
}

// ---------------- fused attention: LDS-staged K/V, balanced qt mapping ----------------
// grid (32,16,4) = 2048 blocks, 4 waves. Work-balanced qt swizzle so each CU's
// blocks span small and large causal depths. K,V double-buffered via
// global_load_lds with pre-swizzled sources; P wave-private in LDS.
__global__ __launch_bounds__(256) void attn_kernel(const ushort_t* __restrict__ Cqkv,
                                                   const ushort_t* __restrict__ Vtg,
                                                   float* __restrict__ Pout,
                                                   ushort_t* __restrict__ Oout) {
    const int S = 2048, DQ = 3072;
    const float C1 = 0.18033688f;   // 0.125 * log2(e)
    const float C2 = 5.77078016f;   // 4 * log2(e)

    int z = (int)blockIdx.x + 32 * (int)blockIdx.y + 512 * (int)blockIdx.z;
    int h = (z >> 5) & 15, b = z >> 9;
    int qt = ((z & 31) + 13 * ((z >> 8) & 7)) & 31;   // balanced bijection
    int q0 = qt * 64;

    int tid = threadIdx.x, wid = tid >> 6, lane = tid & 63;
    int g = lane >> 4, lr = lane & 15;

    __shared__ ushort_t Ks[2][4096];
    __shared__ ushort_t Vs[2][4096];
    __shared__ ushort_t Pb[4096];
    char* PbB = (char*)Pb;

    const ushort_t* Qb = Cqkv + (size_t)b * S * DQ + (size_t)h * 64;
    const ushort_t* Kb = Cqkv + (size_t)b * S * DQ + 1024 + (size_t)h * 64;
    const ushort_t* Vb = Vtg + (size_t)((b * 16 + h) * 64) * 2048;
    float* Pbase = Pout + (((size_t)(b * 16 + h)) * S + q0) * S;

    // staging geometry: tile = 64 rows x 128B; lane covers 16B; wave w owns rows w*8..w*8+7 (+32)
    int srow = lane >> 3;                         // 0..7
    int scol = ((lane & 7) ^ (lane >> 3)) * 8;    // pre-swizzled source col (elems)

    auto stageK = [&](int bufi, int tt) {
        char* dst = (char*)&Ks[bufi][0] + wid * 1024;
        gload_lds16(Kb + (size_t)(tt * 64 + wid * 8 + srow) * DQ + scol, dst);
        gload_lds16(Kb + (size_t)(tt * 64 + 32 + wid * 8 + srow) * DQ + scol, dst + 4096);
    };
    auto stageV = [&](int bufi, int tt) {
        char* dst = (char*)&Vs[bufi][0] + wid * 1024;
        gload_lds16(Vb + (size_t)(wid * 8 + srow) * 2048 + tt * 64 + scol, dst);
        gload_lds16(Vb + (size_t)(32 + wid * 8 + srow) * 2048 + tt * 64 + scol, dst + 4096);
    };

    // Q fragments (registers, whole kernel)
    bf16x8 qf[2];
    {
        const ushort_t* qp = Qb + (size_t)(q0 + wid * 16 + lr) * DQ + g * 8;
        qf[0] = *(const bf16x8*)qp;
        qf[1] = *(const bf16x8*)(qp + 32);
    }
    int qlg = wid * 16 + g * 4;

    // ---- pass 1: per-lane partial sums of exp2(s*C1 - C2) ----
    float psum[4] = {0.f, 0.f, 0.f, 0.f};
    stageK(0, 0);
    __syncthreads();
    int buf = 0;
    for (int tt = 0; tt <= qt; ++tt) {
        if (tt < qt) stageK(buf ^ 1, tt + 1);
        const char* ksb = (const char*)&Ks[buf][0];
#pragma unroll
        for (int nb = 0; nb < 4; ++nb) {
            int row = nb * 16 + lr;
            int x = (row & 7) << 4;
            f32x4 s = {};
            s = __builtin_amdgcn_mfma_f32_16x16x32_bf16(qf[0], *(const bf16x8*)(ksb + row * 128 + ((g * 16) ^ x)), s, 0, 0, 0);
            s = __builtin_amdgcn_mfma_f32_16x16x32_bf16(qf[1], *(const bf16x8*)(ksb + row * 128 + ((64 + g * 16) ^ x)), s, 0, 0, 0);
            if (tt == qt) {
#pragma unroll
                for (int r = 0; r < 4; ++r)
                    if (row <= qlg + r) psum[r] += exp2f(fmaf(s[r], C1, -C2));
            } else {
#pragma unroll
                for (int r = 0; r < 4; ++r) psum[r] += exp2f(fmaf(s[r], C1, -C2));
            }
        }
        __syncthreads();
        buf ^= 1;
    }
    float lnl2[4];
#pragma unroll
    for (int r = 0; r < 4; ++r) {
        float v = psum[r];
        v += __shfl_xor(v, 1); v += __shfl_xor(v, 2);
        v += __shfl_xor(v, 4); v += __shfl_xor(v, 8);
        lnl2[r] = __log2f(v) + C2;
    }

    // ---- pass 2: P = exp2(s*C1 - lnl2), write P + accumulate O ----
    f32x4 Oacc[4] = {};
    stageK(buf, 0);
    stageV(buf, 0);
    __syncthreads();
    for (int tt = 0; tt <= qt; ++tt) {
        if (tt < qt) { stageK(buf ^ 1, tt + 1); stageV(buf ^ 1, tt + 1); }
        const char* ksb = (const char*)&Ks[buf][0];
        const char* vsb = (const char*)&Vs[buf][0];
#pragma unroll
        for (int nb = 0; nb < 4; ++nb) {
            int row = nb * 16 + lr;
            int x = (row & 7) << 4;
            f32x4 s = {};
            s = __builtin_amdgcn_mfma_f32_16x16x32_bf16(qf[0], *(const bf16x8*)(ksb + row * 128 + ((g * 16) ^ x)), s, 0, 0, 0);
            s = __builtin_amdgcn_mfma_f32_16x16x32_bf16(qf[1], *(const bf16x8*)(ksb + row * 128 + ((64 + g * 16) ^ x)), s, 0, 0, 0);
#pragma unroll
            for (int r = 0; r < 4; ++r) {
                float p = exp2f(fmaf(s[r], C1, -lnl2[r]));
                if (tt == qt && (row > qlg + r)) p = 0.f;
                int prow = qlg + r;
                *(ushort_t*)(PbB + ((prow * 128 + row * 2) ^ ((prow & 7) << 4))) = f2b(p);
            }
        }
        __builtin_amdgcn_wave_barrier();
        // PV MFMA (A = this wave's P rows, B = V from LDS)
#pragma unroll
        for (int kc = 0; kc < 2; ++kc) {
            int prow = wid * 16 + lr;
            bf16x8 pf = *(const bf16x8*)(PbB + ((prow * 128 + kc * 64 + g * 16) ^ ((prow & 7) << 4)));
#pragma unroll
            for (int nb = 0; nb < 4; ++nb) {
                int vrow = nb * 16 + lr;
                bf16x8 vf = *(const bf16x8*)(vsb + vrow * 128 + ((kc * 64 + g * 16) ^ ((vrow & 7) << 4)));
                Oacc[nb] = __builtin_amdgcn_mfma_f32_16x16x32_bf16(pf, vf, Oacc[nb], 0, 0, 0);
            }
        }
        // coalesced P global write (64B per lane, per-wave rows)
        {
            int row = wid * 16 + (lane >> 2);
            int c0 = (lane & 3) * 16;
            int x = (row & 7) << 4;
            bf16x8 p0 = *(const bf16x8*)(PbB + ((row * 128 + c0 * 2) ^ x));
            bf16x8 p1 = *(const bf16x8*)(PbB + ((row * 128 + c0 * 2 + 16) ^ x));
            float* dst = Pbase + (size_t)row * S + tt * 64 + c0;
            float4 w;
            w.x = b2f(p0[0]); w.y = b2f(p0[1]); w.z = b2f(p0[2]); w.w = b2f(p0[3]); ((float4*)dst)[0] = w;
            w.x = b2f(p0[4]); w.y = b2f(p0[5]); w.z = b2f(p0[6]); w.w = b2f(p0[7]); ((float4*)dst)[1] = w;
            w.x = b2f(p1[0]); w.y = b2f(p1[1]); w.z = b2f(p1[2]); w.w = b2f(p1[3]); ((float4*)dst)[2] = w;
            w.x = b2f(p1[4]); w.y = b2f(p1[5]); w.z = b2f(p1[6]); w.w = b2f(p1[7]); ((float4*)dst)[3] = w;
        }
        __syncthreads();
        buf ^= 1;
    }

    // zero-fill strictly-upper tiles
    {
        int vsr = tid >> 2, vsc = (tid & 3) * 16;
        float4 zf = {0.f, 0.f, 0.f, 0.f};
        for (int tt = qt + 1; tt < 32; ++tt) {
            float* dst = Pbase + (size_t)vsr * S + tt * 64 + vsc;
#pragma unroll
            for (int j = 0; j < 4; ++j) ((float4*)dst)[j] = zf;
        }
    }

    // write O (bf16) as [B,S,H*Dh]
#pragma unroll
    for (int nb = 0; nb < 4; ++nb)
#pragma unroll
        for (int r = 0; r < 4; ++r) {
            int q = q0 + qlg + r;
            Oout[((size_t)b * S + q) * 1024 + h * 64 + nb * 16 + lr] = f2b(Oacc[nb][r]);
        }
}

extern "C" void kernel_launch(void* const* d_in, const int* in_sizes, int n_in,
                              void* d_out, int out_size, void* d_ws, size_t ws_size,
                              hipStream_t stream) {
    const float* x  = (const float*)d_in[0];
    const float* Wq = (const float*)d_in[1];
    const float* Wk = (const float*)d_in[2];
    const float* Wv = (const float*)d_in[3];
    const float* Wo = (const float*)d_in[4];
    const float* bo = (const float*)d_in[5];

    float* out  = (float*)d_out;
    float* Pout = out + (size_t)8388608; // attn_probs region

    char* ws = (char*)d_ws;
    ushort_t* xb    = (ushort_t*)(ws);                       // 16 MB
    ushort_t* wqkv  = (ushort_t*)(ws + (16u << 20));         // 6 MB [3072][1024]
    ushort_t* wob   = (ushort_t*)(ws + (22u << 20));         // 2 MB
    ushort_t* Cqkv  = (ushort_t*)(ws + (24u << 20));         // 48 MB [8192][3072]
    ushort_t* Vtw   = (ushort_t*)(ws + (72u << 20));         // 32 MB [b*h][64][2048]
    ushort_t* attnb = (ushort_t*)(ws + (104u << 20));        // 16 MB

    // 1. dtype conversions / weight transposes
    convert_x_kernel<<<8192, 256, 0, stream>>>(x, xb, 2097152);
    transpose_w_kernel<<<dim3(32, 32), dim3(32, 8), 0, stream>>>(Wq, wqkv);
    transpose_w_kernel<<<dim3(32, 32), dim3(32, 8), 0, stream>>>(Wk, wqkv + 1024 * 1024);
    transpose_w_kernel<<<dim3(32, 32), dim3(32, 8), 0, stream>>>(Wv, wqkv + 2 * 1024 * 1024);
    transpose_w_kernel<<<dim3(32, 32), dim3(32, 8), 0, stream>>>(Wo, wob);

    // 2. fused QKV projection: Cqkv[8192][3072]
    gemm_kernel<3072, 1><<<dim3(64, 24), 256, 0, stream>>>(xb, wqkv, Cqkv, nullptr, nullptr);

    // 3. V transpose to [b][h][d][s]
    vt_kernel<<<dim3(32, 16, 4), 256, 0, stream>>>(Cqkv, Vtw);

    // 4. attention (writes attn_probs fp32 + context bf16)
    attn_kernel<<<dim3(32, 16, 4), 256, 0, stream>>>(Cqkv, Vtw, Pout, attnb);

    // 5. output projection + bias (fp32 out)
    gemm_kernel<1024, 0><<<dim3(64, 8), 256, 0, stream>>>(attnb, wob, nullptr, out, bo);
}

// Round 5
// 485.819 us; speedup vs baseline: 1.9982x; 1.1450x over previous
//
#include <hip/hip_runtime.h>
#include <hip/hip_bf16.h>

typedef __attribute__((ext_vector_type(8))) short bf16x8;
typedef __attribute__((ext_vector_type(4))) float f32x4;
typedef unsigned short ushort_t;
typedef unsigned int uint_t;

#define AS1 __attribute__((address_space(1)))
#define AS3 __attribute__((address_space(3)))

__device__ __forceinline__ void gload_lds16(const void* g, void* l) {
    __builtin_amdgcn_global_load_lds((const AS1 void*)g, (AS3 void*)l, 16, 0, 0);
}

__device__ __forceinline__ ushort_t f2b(float f) {
    unsigned u = __builtin_bit_cast(unsigned, f);
    unsigned r = (u + 0x7FFFu + ((u >> 16) & 1u)) >> 16;
    return (ushort_t)r;
}

// ---------------- convert x (fp32 -> bf16) ----------------
__global__ __launch_bounds__(256) void convert_x_kernel(const float* __restrict__ in,
                                                        ushort_t* __restrict__ out, int n4) {
    int i = blockIdx.x * blockDim.x + threadIdx.x;
    if (i < n4) {
        float4 f = ((const float4*)in)[i];
        ushort4 u;
        u.x = f2b(f.x); u.y = f2b(f.y); u.z = f2b(f.z); u.w = f2b(f.w);
        ((ushort4*)out)[i] = u;
    }
}

// ---------------- transpose + convert weight: W[K][N] fp32 -> WT[N][K] bf16 ----------------
__global__ __launch_bounds__(256) void transpose_w_kernel(const float* __restrict__ W,
                                                          ushort_t* __restrict__ WT) {
    __shared__ float t[32][33];
    int n0 = blockIdx.x * 32, k0 = blockIdx.y * 32;
    int tx = threadIdx.x, ty = threadIdx.y; // block (32,8)
    for (int i = 0; i < 4; ++i)
        t[ty + i * 8][tx] = W[(size_t)(k0 + ty + i * 8) * 1024 + n0 + tx];
    __syncthreads();
    for (int i = 0; i < 4; ++i)
        WT[(size_t)(n0 + ty + i * 8) * 1024 + k0 + tx] = f2b(t[tx][ty + i * 8]);
}

// ---------------- bf16 MFMA GEMM, 2-phase dbuf global_load_lds ----------------
template <int N, int OUT_BF16>
__global__ __launch_bounds__(256) void gemm_kernel(const ushort_t* __restrict__ A,
                                                   const ushort_t* __restrict__ BT,
                                                   ushort_t* __restrict__ Cb,
                                                   float* __restrict__ Cf,
                                                   const float* __restrict__ bias) {
    const int K = 1024;
    __shared__ ushort_t As[2 * 128 * 32];
    __shared__ ushort_t Bs[2 * 128 * 32];
    int tid = threadIdx.x;
    int wid = tid >> 6, lane = tid & 63;
    int g = lane >> 4, lr = lane & 15;
    int m0 = blockIdx.x * 128, n0 = blockIdx.y * 128;
    int wm = wid >> 1, wn = wid & 1;

    f32x4 acc[4][4] = {};

    int c0 = wid * 2;
    int lrow = lane >> 2;
    int lcol = ((lane & 3) ^ ((lane >> 3) & 3)) * 8;
    const ushort_t* Ag0 = A  + (size_t)(m0 + c0 * 16 + lrow) * K + lcol;
    const ushort_t* Ag1 = A  + (size_t)(m0 + c0 * 16 + 16 + lrow) * K + lcol;
    const ushort_t* Bg0 = BT + (size_t)(n0 + c0 * 16 + lrow) * K + lcol;
    const ushort_t* Bg1 = BT + (size_t)(n0 + c0 * 16 + 16 + lrow) * K + lcol;

    int swzA = ((lr >> 1) & 3) << 4;

    auto stage = [&](int bufi, int kt) {
        char* a0 = (char*)As + bufi * 8192 + c0 * 1024;
        char* b0 = (char*)Bs + bufi * 8192 + c0 * 1024;
        gload_lds16(Ag0 + kt * 32, a0);
        gload_lds16(Ag1 + kt * 32, a0 + 1024);
        gload_lds16(Bg0 + kt * 32, b0);
        gload_lds16(Bg1 + kt * 32, b0 + 1024);
    };

    stage(0, 0);
    __syncthreads();
    int buf = 0;
    for (int kt = 0; kt < K / 32; ++kt) {
        if (kt + 1 < K / 32) stage(buf ^ 1, kt + 1);
        const char* ab = (const char*)As + buf * 8192;
        const char* bb = (const char*)Bs + buf * 8192;
        bf16x8 af[4], bfr[4];
#pragma unroll
        for (int m = 0; m < 4; ++m) {
            int row = wm * 64 + m * 16 + lr;
            af[m] = *(const bf16x8*)(ab + row * 64 + ((g * 16) ^ swzA));
        }
#pragma unroll
        for (int n = 0; n < 4; ++n) {
            int row = wn * 64 + n * 16 + lr;
            bfr[n] = *(const bf16x8*)(bb + row * 64 + ((g * 16) ^ swzA));
        }
#pragma unroll
        for (int m = 0; m < 4; ++m)
#pragma unroll
            for (int n = 0; n < 4; ++n)
                acc[m][n] = __builtin_amdgcn_mfma_f32_16x16x32_bf16(af[m], bfr[n], acc[m][n], 0, 0, 0);
        __syncthreads();
        buf ^= 1;
    }

#pragma unroll
    for (int m = 0; m < 4; ++m)
#pragma unroll
        for (int n = 0; n < 4; ++n) {
            int row0 = m0 + wm * 64 + m * 16 + g * 4;
            int col  = n0 + wn * 64 + n * 16 + lr;
#pragma unroll
            for (int r = 0; r < 4; ++r) {
                float v = acc[m][n][r];
                if (OUT_BF16)
                    Cb[(size_t)(row0 + r) * N + col] = f2b(v);
                else
                    Cf[(size_t)(row0 + r) * N + col] = v + bias[col];
            }
        }
}

// ---------------- V transpose: Cqkv V-part [s][d] -> Vt[b][h][d][s] bf16 ----------------
__global__ __launch_bounds__(256) void vt_kernel(const ushort_t* __restrict__ Cqkv,
                                                 ushort_t* __restrict__ Vt) {
    int b = blockIdx.z, h = blockIdx.y, st = blockIdx.x;
    __shared__ ushort_t t[64][72];
    const ushort_t* src = Cqkv + (size_t)b * 2048 * 3072 + 2048 + (size_t)h * 64;
    int tid = threadIdx.x;
#pragma unroll
    for (int i = 0; i < 2; ++i) {
        int c = tid + i * 256;
        int sl = c >> 3, dc = (c & 7) * 8;
        *(bf16x8*)&t[sl][dc] = *(const bf16x8*)(src + (size_t)(st * 64 + sl) * 3072 + dc);
    }
    __syncthreads();
#pragma unroll
    for (int i = 0; i < 2; ++i) {
        int c = tid + i * 256;
        int d = c >> 3, sc = (c & 7) * 8;
        bf16x8 v;
#pragma unroll
        for (int j = 0; j < 8; ++j) v[j] = (short)t[sc + j][d];
        *(bf16x8*)(Vt + ((size_t)(b * 16 + h) * 64 + d) * 2048 + st * 64 + sc) = v;
    }
}

// ---------------- fused attention: swapped-operand QK^T, lane-local P rows ----------------
// grid (32,16,4), 4 waves. Each lane owns ONE q-row (q = wid*16 + lane&15):
// S^T fragments give 16 P elements/lane -> scalar softmax sum, direct f32x4
// P stores, tiny LDS repack for the PV A-operand.
__global__ __launch_bounds__(256) void attn_kernel(const ushort_t* __restrict__ Cqkv,
                                                   const ushort_t* __restrict__ Vtg,
                                                   float* __restrict__ Pout,
                                                   ushort_t* __restrict__ Oout) {
    const int S = 2048, DQ = 3072;
    const float C1 = 0.18033688f;   // 0.125 * log2(e)
    const float C2 = 5.77078016f;   // 4 * log2(e)

    int z = (int)blockIdx.x + 32 * (int)blockIdx.y + 512 * (int)blockIdx.z;
    int h = (z >> 5) & 15, b = z >> 9;
    int qt = ((z & 31) + 13 * ((z >> 8) & 7)) & 31;   // balanced bijection
    int q0 = qt * 64;

    int tid = threadIdx.x, wid = tid >> 6, lane = tid & 63;
    int g = lane >> 4, lr = lane & 15;

    __shared__ ushort_t Ks[2][4096];
    __shared__ ushort_t Vs[2][4096];
    __shared__ ushort_t Pl[4096];              // 4 waves x [16 q][64 t] bf16
    char* PlB = (char*)Pl + wid * 2048;

    const ushort_t* Qb = Cqkv + (size_t)b * S * DQ + (size_t)h * 64;
    const ushort_t* Kb = Cqkv + (size_t)b * S * DQ + 1024 + (size_t)h * 64;
    const ushort_t* Vb = Vtg + (size_t)((b * 16 + h) * 64) * 2048;
    float* Pbase = Pout + (((size_t)(b * 16 + h)) * S + q0) * S;

    // staging geometry: tile 64 rows x 128B; lane covers 16B; wave w owns rows w*8..w*8+7 (+32)
    int srow = lane >> 3;
    int scol = ((lane & 7) ^ srow) * 8;   // pre-swizzled source chunk

    auto stageK = [&](int bufi, int tt) {
        char* dst = (char*)&Ks[bufi][0] + wid * 1024;
        gload_lds16(Kb + (size_t)(tt * 64 + wid * 8 + srow) * DQ + scol, dst);
        gload_lds16(Kb + (size_t)(tt * 64 + 32 + wid * 8 + srow) * DQ + scol, dst + 4096);
    };
    auto stageV = [&](int bufi, int tt) {
        char* dst = (char*)&Vs[bufi][0] + wid * 1024;
        gload_lds16(Vb + (size_t)(wid * 8 + srow) * 2048 + tt * 64 + scol, dst);
        gload_lds16(Vb + (size_t)(32 + wid * 8 + srow) * 2048 + tt * 64 + scol, dst + 4096);
    };

    // Q fragments (registers, whole kernel) — B-operand: col=lr -> q row, k = kc*32+g*8
    bf16x8 qf[2];
    {
        const ushort_t* qp = Qb + (size_t)(q0 + wid * 16 + lr) * DQ + g * 8;
        qf[0] = *(const bf16x8*)qp;
        qf[1] = *(const bf16x8*)(qp + 32);
    }
    int qloc = wid * 16 + lr;   // this lane's q row (local 0..63)

    // ---- pass 1: per-lane sum of exp2(s*C1 - C2) over all t ----
    float psum = 0.f;
    stageK(0, 0);
    __syncthreads();
    int buf = 0;
    for (int tt = 0; tt <= qt; ++tt) {
        if (tt < qt) stageK(buf ^ 1, tt + 1);
        const char* ksb = (const char*)&Ks[buf][0];
#pragma unroll
        for (int nb = 0; nb < 4; ++nb) {
            int row = nb * 16 + lr;
            int x = (row & 7) << 4;
            f32x4 s = {};
            s = __builtin_amdgcn_mfma_f32_16x16x32_bf16(*(const bf16x8*)(ksb + row * 128 + ((g * 16) ^ x)), qf[0], s, 0, 0, 0);
            s = __builtin_amdgcn_mfma_f32_16x16x32_bf16(*(const bf16x8*)(ksb + row * 128 + ((64 + g * 16) ^ x)), qf[1], s, 0, 0, 0);
            if (tt == qt) {
#pragma unroll
                for (int r = 0; r < 4; ++r)
                    if (nb * 16 + g * 4 + r <= qloc) psum += exp2f(fmaf(s[r], C1, -C2));
            } else {
#pragma unroll
                for (int r = 0; r < 4; ++r) psum += exp2f(fmaf(s[r], C1, -C2));
            }
        }
        __syncthreads();
        buf ^= 1;
    }
    psum += __shfl_xor(psum, 16);
    psum += __shfl_xor(psum, 32);
    float lnl2 = __log2f(psum) + C2;

    // ---- pass 2: P = exp2(s*C1 - lnl2); direct f32 stores; LDS repack for PV ----
    f32x4 Oacc[4] = {};
    stageK(buf, 0);
    stageV(buf, 0);
    __syncthreads();
    for (int tt = 0; tt <= qt; ++tt) {
        if (tt < qt) { stageK(buf ^ 1, tt + 1); stageV(buf ^ 1, tt + 1); }
        const char* ksb = (const char*)&Ks[buf][0];
        const char* vsb = (const char*)&Vs[buf][0];
        f32x4 p[4];
#pragma unroll
        for (int nb = 0; nb < 4; ++nb) {
            int row = nb * 16 + lr;
            int x = (row & 7) << 4;
            f32x4 s = {};
            s = __builtin_amdgcn_mfma_f32_16x16x32_bf16(*(const bf16x8*)(ksb + row * 128 + ((g * 16) ^ x)), qf[0], s, 0, 0, 0);
            s = __builtin_amdgcn_mfma_f32_16x16x32_bf16(*(const bf16x8*)(ksb + row * 128 + ((64 + g * 16) ^ x)), qf[1], s, 0, 0, 0);
#pragma unroll
            for (int r = 0; r < 4; ++r) {
                float v = exp2f(fmaf(s[r], C1, -lnl2));
                if (tt == qt && (nb * 16 + g * 4 + r > qloc)) v = 0.f;
                p[nb][r] = v;
            }
        }
        // direct P global stores (f32, 64B/row per wave, fully coalesced)
#pragma unroll
        for (int nb = 0; nb < 4; ++nb)
            *(f32x4*)(Pbase + (size_t)qloc * S + tt * 64 + nb * 16 + g * 4) = p[nb];
        // pack to bf16 and repack via tiny LDS tile (wave-private)
#pragma unroll
        for (int nb = 0; nb < 4; ++nb) {
            uint_t w0, w1;
            asm("v_cvt_pk_bf16_f32 %0, %1, %2" : "=v"(w0) : "v"(p[nb][0]), "v"(p[nb][1]));
            asm("v_cvt_pk_bf16_f32 %0, %1, %2" : "=v"(w1) : "v"(p[nb][2]), "v"(p[nb][3]));
            uint2 w; w.x = w0; w.y = w1;
            *(uint2*)(PlB + ((lr * 128 + nb * 32 + g * 8) ^ ((lr & 7) << 4))) = w;
        }
        __builtin_amdgcn_wave_barrier();
        // PV MFMA: A = repacked P rows, B = V fragments from LDS
#pragma unroll
        for (int kc = 0; kc < 2; ++kc) {
            bf16x8 pf = *(const bf16x8*)(PlB + ((lr * 128 + kc * 64 + g * 16) ^ ((lr & 7) << 4)));
#pragma unroll
            for (int nb = 0; nb < 4; ++nb) {
                int vrow = nb * 16 + lr;
                bf16x8 vf = *(const bf16x8*)(vsb + vrow * 128 + ((kc * 64 + g * 16) ^ ((vrow & 7) << 4)));
                Oacc[nb] = __builtin_amdgcn_mfma_f32_16x16x32_bf16(pf, vf, Oacc[nb], 0, 0, 0);
            }
        }
        // counted drain: the 8 K/V prefetch loads must land (cross-wave LDS),
        // but the 4 P stores may linger (<=4 outstanding).
        asm volatile("s_waitcnt vmcnt(4)" ::: "memory");
        __builtin_amdgcn_s_barrier();
        __builtin_amdgcn_sched_barrier(0);
        buf ^= 1;
    }

    // zero-fill strictly-upper tiles
    {
        int vsr = tid >> 2, vsc = (tid & 3) * 16;
        float4 zf = {0.f, 0.f, 0.f, 0.f};
        for (int tt = qt + 1; tt < 32; ++tt) {
            float* dst = Pbase + (size_t)vsr * S + tt * 64 + vsc;
#pragma unroll
            for (int j = 0; j < 4; ++j) ((float4*)dst)[j] = zf;
        }
    }

    // write O (bf16) as [B,S,H*Dh]: lane holds O[q=g*4+r][d=lr] per nb d-block
#pragma unroll
    for (int nb = 0; nb < 4; ++nb)
#pragma unroll
        for (int r = 0; r < 4; ++r) {
            int q = q0 + wid * 16 + g * 4 + r;
            Oout[((size_t)b * S + q) * 1024 + h * 64 + nb * 16 + lr] = f2b(Oacc[nb][r]);
        }
}

extern "C" void kernel_launch(void* const* d_in, const int* in_sizes, int n_in,
                              void* d_out, int out_size, void* d_ws, size_t ws_size,
                              hipStream_t stream) {
    const float* x  = (const float*)d_in[0];
    const float* Wq = (const float*)d_in[1];
    const float* Wk = (const float*)d_in[2];
    const float* Wv = (const float*)d_in[3];
    const float* Wo = (const float*)d_in[4];
    const float* bo = (const float*)d_in[5];

    float* out  = (float*)d_out;
    float* Pout = out + (size_t)8388608; // attn_probs region

    char* ws = (char*)d_ws;
    ushort_t* xb    = (ushort_t*)(ws);                       // 16 MB
    ushort_t* wqkv  = (ushort_t*)(ws + (16u << 20));         // 6 MB [3072][1024]
    ushort_t* wob   = (ushort_t*)(ws + (22u << 20));         // 2 MB
    ushort_t* Cqkv  = (ushort_t*)(ws + (24u << 20));         // 48 MB [8192][3072]
    ushort_t* Vtw   = (ushort_t*)(ws + (72u << 20));         // 32 MB [b*h][64][2048]
    ushort_t* attnb = (ushort_t*)(ws + (104u << 20));        // 16 MB

    // 1. dtype conversions / weight transposes
    convert_x_kernel<<<8192, 256, 0, stream>>>(x, xb, 2097152);
    transpose_w_kernel<<<dim3(32, 32), dim3(32, 8), 0, stream>>>(Wq, wqkv);
    transpose_w_kernel<<<dim3(32, 32), dim3(32, 8), 0, stream>>>(Wk, wqkv + 1024 * 1024);
    transpose_w_kernel<<<dim3(32, 32), dim3(32, 8), 0, stream>>>(Wv, wqkv + 2 * 1024 * 1024);
    transpose_w_kernel<<<dim3(32, 32), dim3(32, 8), 0, stream>>>(Wo, wob);

    // 2. fused QKV projection: Cqkv[8192][3072]
    gemm_kernel<3072, 1><<<dim3(64, 24), 256, 0, stream>>>(xb, wqkv, Cqkv, nullptr, nullptr);

    // 3. V transpose to [b][h][d][s]
    vt_kernel<<<dim3(32, 16, 4), 256, 0, stream>>>(Cqkv, Vtw);

    // 4. attention (writes attn_probs fp32 + context bf16)
    attn_kernel<<<dim3(32, 16, 4), 256, 0, stream>>>(Cqkv, Vtw, Pout, attnb);

    // 5. output projection + bias (fp32 out)
    gemm_kernel<1024, 0><<<dim3(64, 8), 256, 0, stream>>>(attnb, wob, nullptr, out, bo);
}